// Round 23
// baseline (121.372 us; speedup 1.0000x reference)
//
#include <hip/hip_runtime.h>
#include <hip/hip_fp16.h>

#define N_NODES 100000
#define N_EDGES 1600000
#define IN_DIM 165
#define HID 64
#define OUT_DIM 2
#define NB ((N_NODES + 127) / 128)               // 782 buckets of 128 nodes
#define CAP 3072                                  // fixed bucket capacity (mean 2048, +22 sigma)
#define EPB 4096                                  // edges per bin block
#define BIN_BLOCKS ((N_EDGES + EPB - 1) / EPB)   // 391
#define KP 64                                     // k-phase (3*64 = 192 >= 165, zero-padded)
#define XST 72                                    // xs row stride in halves (bank-safe)

typedef _Float16 f16x8 __attribute__((ext_vector_type(8)));
typedef float f32x4 __attribute__((ext_vector_type(4)));

// ---- Pass A: bin edges into 782 fixed-capacity bucket regions ----
// Block-local counting sort in LDS, coalesced run write-out.
__global__ __launch_bounds__(512) void k_bin(const int* __restrict__ src,
                                             const int* __restrict__ dst,
                                             int* __restrict__ bcnt,
                                             unsigned int* __restrict__ rec) {
    __shared__ int hist[NB];
    __shared__ int rstart[NB];
    __shared__ int gbase[NB];
    __shared__ int cur[NB];
    __shared__ int tsum[512];
    __shared__ unsigned int lrec[EPB];        // 16 KB
    __shared__ unsigned short lbkt[EPB];      // 8 KB
    const int tid = threadIdx.x;
    for (int b = tid; b < NB; b += 512) { hist[b] = 0; cur[b] = 0; }
    __syncthreads();
    const int e0 = blockIdx.x * EPB;
    const int total = min(EPB, N_EDGES - e0);
    for (int j = tid; j < total; j += 512)
        atomicAdd(&hist[dst[e0 + j] >> 7], 1);
    __syncthreads();
    int own[2];
    int s = 0;
    #pragma unroll
    for (int u = 0; u < 2; ++u) {
        int idx = tid * 2 + u;
        own[u] = s;
        s += (idx < NB) ? hist[idx] : 0;
    }
    tsum[tid] = s;
    __syncthreads();
    for (int off = 1; off < 512; off <<= 1) {
        int t = (tid >= off) ? tsum[tid - off] : 0;
        __syncthreads();
        tsum[tid] += t;
        __syncthreads();
    }
    int prev = (tid > 0) ? tsum[tid - 1] : 0;
    #pragma unroll
    for (int u = 0; u < 2; ++u) {
        int idx = tid * 2 + u;
        if (idx < NB) rstart[idx] = prev + own[u];
    }
    for (int b = tid; b < NB; b += 512)
        if (hist[b] > 0) gbase[b] = atomicAdd(&bcnt[b], hist[b]);
    __syncthreads();
    for (int j = tid; j < total; j += 512) {
        int d = dst[e0 + j], sv = src[e0 + j];
        int b = d >> 7;
        int off = atomicAdd(&cur[b], 1);
        int slot = rstart[b] + off;
        lrec[slot] = (unsigned int)sv | ((unsigned int)(d & 127) << 17);
        lbkt[slot] = (unsigned short)b;
    }
    __syncthreads();
    for (int slot = tid; slot < total; slot += 512) {
        int b = lbkt[slot];
        int pos = gbase[b] + (slot - rstart[b]);
        rec[(size_t)b * CAP + pos] = lrec[slot];
    }
}

// ---- Pass B: per-bucket sort; block computes its own CSR base (no bscan) ----
__global__ __launch_bounds__(512) void k_sort2(const int* __restrict__ bcnt,
                                               const unsigned int* __restrict__ rec,
                                               int* __restrict__ row_ptr,
                                               float* __restrict__ dinv,
                                               int* __restrict__ esrc) {
    __shared__ int hist[128];
    __shared__ int scn[128];
    __shared__ int cur[128];
    __shared__ int tsum[512];
    const int tid = threadIdx.x;
    const int b = blockIdx.x;
    const int n0 = b << 7;
    if (tid < 128) { hist[tid] = 0; cur[tid] = 0; }
    // gb = sum of bcnt[0..b)  (bcnt final at kernel boundary; L2-hot)
    int part = 0;
    for (int j = tid; j < b; j += 512) part += bcnt[j];
    tsum[tid] = part;
    __syncthreads();
    for (int off = 256; off >= 1; off >>= 1) {
        if (tid < off) tsum[tid] += tsum[tid + off];
        __syncthreads();
    }
    const int gb = tsum[0];
    const int cb = bcnt[b];
    const size_t s0 = (size_t)b * CAP;
    // read records ONCE into fixed-index registers + histogram
    unsigned int rv[6];   // 6*512 = 3072 = CAP
    #pragma unroll
    for (int u = 0; u < 6; ++u) {
        int i = tid + (u << 9);
        rv[u] = 0;
        if (i < cb) {
            rv[u] = rec[s0 + i];
            atomicAdd(&hist[rv[u] >> 17], 1);
        }
    }
    __syncthreads();
    int v = (tid < 128) ? hist[tid] : 0;
    if (tid < 128) scn[tid] = v;
    __syncthreads();
    for (int off = 1; off < 128; off <<= 1) {
        int t = (tid >= off && tid < 128) ? scn[tid - off] : 0;
        __syncthreads();
        if (tid < 128) scn[tid] += t;
        __syncthreads();
    }
    if (tid < 128) {
        int n = n0 + tid;
        if (n < N_NODES) {
            row_ptr[n] = gb + scn[tid] - v;            // exclusive base
            dinv[n] = rsqrtf((float)v + 1.0f);
        }
    }
    if (b == NB - 1 && tid == 0) row_ptr[N_NODES] = N_EDGES;
    __syncthreads();
    // place from registers
    #pragma unroll
    for (int u = 0; u < 6; ++u) {
        int i = tid + (u << 9);
        if (i < cb) {
            int ld = (int)(rv[u] >> 17);
            int pos = gb + (scn[ld] - hist[ld]) + atomicAdd(&cur[ld], 1);
            esrc[pos] = (int)(rv[u] & 131071u);
        }
    }
}

// ------- GEMM1 via MFMA: hw1h = fp16((x@W1)*dinv), 32-row tile -------
__global__ __launch_bounds__(256) void k_gemm1(const float* __restrict__ x,
                                               const float* __restrict__ W1,
                                               const float* __restrict__ dinv,
                                               __half* __restrict__ hw1h) {
    __shared__ __align__(16) _Float16 xs[32 * XST];      // 4608 B
    __shared__ __align__(16) _Float16 wsf[8 * 64 * 8];   // 8192 B
    const int tid = threadIdx.x;
    const int lane = tid & 63;
    const int wave = tid >> 6;
    const int lg = lane >> 4;
    const int lm = lane & 15;
    const int mt = wave >> 1;     // M-tile (16 rows)
    const int nh = wave & 1;      // N-half (32 cols)
    const int base = blockIdx.x * 32;
    const int nrows = min(32, N_NODES - base);

    const int srow = tid >> 3;
    const int sseg = (tid & 7) * 8;
    const int src_r = min(srow, nrows - 1);
    const float* xrow = x + (size_t)(base + src_r) * IN_DIM;
    const bool rvalid = (srow < nrows);

    f32x4 acc[2] = {};

    for (int p = 0; p < 3; ++p) {
        const int k0 = p * KP;
        #pragma unroll
        for (int u = 0; u < 8; ++u) {
            int kk = sseg + u;
            int k = k0 + kk;
            float v = xrow[min(k, IN_DIM - 1)];
            xs[srow * XST + kk] = (rvalid && k < IN_DIM) ? (_Float16)v : (_Float16)0.f;
        }
        #pragma unroll
        for (int it = 0; it < 2; ++it) {
            int idx = tid + 256 * it;
            int g = idx >> 6;
            int n = idx & 63;
            f16x8 frag;
            #pragma unroll
            for (int j = 0; j < 8; ++j) {
                int k = k0 + 8 * g + j;
                float v = W1[(size_t)min(k, IN_DIM - 1) * HID + n];
                frag[j] = (k < IN_DIM) ? (_Float16)v : (_Float16)0.f;
            }
            *(f16x8*)&wsf[((g << 6) + n) * 8] = frag;
        }
        __syncthreads();
        #pragma unroll
        for (int s = 0; s < 2; ++s) {
            f16x8 af = *(const f16x8*)&xs[(16 * mt + lm) * XST + 32 * s + 8 * lg];
            #pragma unroll
            for (int nb = 0; nb < 2; ++nb) {
                int nt = 2 * nh + nb;
                f16x8 bf = *(const f16x8*)&wsf[(((s << 2) + lg) * 64 + (nt << 4) + lm) * 8];
                acc[nb] = __builtin_amdgcn_mfma_f32_16x16x32_f16(af, bf, acc[nb], 0, 0, 0);
            }
        }
        __syncthreads();
    }

    #pragma unroll
    for (int r = 0; r < 4; ++r) {
        int grow = base + 16 * mt + 4 * lg + r;
        if (grow < N_NODES) {
            float dv = dinv[grow];
            #pragma unroll
            for (int nb = 0; nb < 2; ++nb) {
                int nt = 2 * nh + nb;
                hw1h[(size_t)grow * HID + (nt << 4) + lm] = __float2half(acc[nb][r] * dv);
            }
        }
    }
}

// ---- layer-1 gather (fp16 rows, 16/8/4-deep MLP) + bias/relu + W2 + pre-scale ----
__global__ __launch_bounds__(256) void k_gather1(const int* __restrict__ row_ptr,
                                                 const int* __restrict__ esrc,
                                                 const __half* __restrict__ hw1h,
                                                 const float* __restrict__ dinv,
                                                 const float* __restrict__ b1,
                                                 const float* __restrict__ W2,
                                                 float* __restrict__ hw2s) {
    __shared__ float w2s[HID * OUT_DIM];
    __shared__ float b1s[HID];
    const int tid = threadIdx.x;
    if (tid < HID * OUT_DIM) w2s[tid] = W2[tid];
    if (tid < HID) b1s[tid] = b1[tid];
    __syncthreads();

    const int node = blockIdx.x * 16 + (tid >> 4);
    const int q = tid & 15;
    if (node >= N_NODES) return;
    const int beg = row_ptr[node], end = row_ptr[node + 1];
    float4 acc = {0.f, 0.f, 0.f, 0.f};
    int i = beg;
    for (; i + 15 < end; i += 16) {
        uint2 u[16];
        #pragma unroll
        for (int e = 0; e < 16; ++e) {
            int s = esrc[i + e];
            u[e] = *(const uint2*)&hw1h[(size_t)s * HID + 4 * q];
        }
        #pragma unroll
        for (int e = 0; e < 16; ++e) {
            float2 a0 = __half22float2(*(const __half2*)&u[e].x);
            float2 a1 = __half22float2(*(const __half2*)&u[e].y);
            acc.x += a0.x; acc.y += a0.y; acc.z += a1.x; acc.w += a1.y;
        }
    }
    for (; i + 7 < end; i += 8) {
        uint2 u[8];
        #pragma unroll
        for (int e = 0; e < 8; ++e) {
            int s = esrc[i + e];
            u[e] = *(const uint2*)&hw1h[(size_t)s * HID + 4 * q];
        }
        #pragma unroll
        for (int e = 0; e < 8; ++e) {
            float2 a0 = __half22float2(*(const __half2*)&u[e].x);
            float2 a1 = __half22float2(*(const __half2*)&u[e].y);
            acc.x += a0.x; acc.y += a0.y; acc.z += a1.x; acc.w += a1.y;
        }
    }
    for (; i + 3 < end; i += 4) {
        uint2 u[4];
        #pragma unroll
        for (int e = 0; e < 4; ++e) {
            int s = esrc[i + e];
            u[e] = *(const uint2*)&hw1h[(size_t)s * HID + 4 * q];
        }
        #pragma unroll
        for (int e = 0; e < 4; ++e) {
            float2 a0 = __half22float2(*(const __half2*)&u[e].x);
            float2 a1 = __half22float2(*(const __half2*)&u[e].y);
            acc.x += a0.x; acc.y += a0.y; acc.z += a1.x; acc.w += a1.y;
        }
    }
    for (; i < end; ++i) {
        int s = esrc[i];
        uint2 u = *(const uint2*)&hw1h[(size_t)s * HID + 4 * q];
        float2 a0 = __half22float2(*(const __half2*)&u.x);
        float2 a1 = __half22float2(*(const __half2*)&u.y);
        acc.x += a0.x; acc.y += a0.y; acc.z += a1.x; acc.w += a1.y;
    }
    const float dv = dinv[node];
    uint2 us = *(const uint2*)&hw1h[(size_t)node * HID + 4 * q];
    float2 h0 = __half22float2(*(const __half2*)&us.x);
    float2 h1 = __half22float2(*(const __half2*)&us.y);
    float h[4];
    h[0] = fmaxf(dv * (acc.x + h0.x) + b1s[4 * q + 0], 0.f);
    h[1] = fmaxf(dv * (acc.y + h0.y) + b1s[4 * q + 1], 0.f);
    h[2] = fmaxf(dv * (acc.z + h1.x) + b1s[4 * q + 2], 0.f);
    h[3] = fmaxf(dv * (acc.w + h1.y) + b1s[4 * q + 3], 0.f);
    float s0 = 0.f, s1 = 0.f;
    #pragma unroll
    for (int k = 0; k < 4; ++k) {
        int j = 4 * q + k;
        s0 += h[k] * w2s[2 * j + 0];
        s1 += h[k] * w2s[2 * j + 1];
    }
    #pragma unroll
    for (int off = 8; off >= 1; off >>= 1) {
        s0 += __shfl_down(s0, off, 16);
        s1 += __shfl_down(s1, off, 16);
    }
    if (q == 0) {
        hw2s[(size_t)node * 2 + 0] = s0 * dv;
        hw2s[(size_t)node * 2 + 1] = s1 * dv;
    }
}

// ---- layer-2 gather (4 lanes/node) + final bias ----
__global__ __launch_bounds__(256) void k_gather2(const int* __restrict__ row_ptr,
                                                 const int* __restrict__ esrc,
                                                 const float* __restrict__ hw2s,
                                                 const float* __restrict__ dinv,
                                                 const float* __restrict__ b2,
                                                 float* __restrict__ out) {
    const int tid = threadIdx.x;
    const int node = blockIdx.x * 64 + (tid >> 2);
    const int e4 = tid & 3;
    if (node >= N_NODES) return;
    const int beg = row_ptr[node], end = row_ptr[node + 1];
    float a0 = 0.f, a1 = 0.f;
    for (int i = beg + e4; i < end; i += 4) {
        int s = esrc[i];
        float2 v = *(const float2*)&hw2s[(size_t)s * 2];
        a0 += v.x;
        a1 += v.y;
    }
    a0 += __shfl_xor(a0, 1, 4); a0 += __shfl_xor(a0, 2, 4);
    a1 += __shfl_xor(a1, 1, 4); a1 += __shfl_xor(a1, 2, 4);
    if (e4 == 0) {
        float dv = dinv[node];
        float2 sv = *(const float2*)&hw2s[(size_t)node * 2];
        out[(size_t)node * 2 + 0] = dv * (a0 + sv.x) + b2[0];
        out[(size_t)node * 2 + 1] = dv * (a1 + sv.y) + b2[1];
    }
}

extern "C" void kernel_launch(void* const* d_in, const int* in_sizes, int n_in,
                              void* d_out, int out_size, void* d_ws, size_t ws_size,
                              hipStream_t stream) {
    const float* x  = (const float*)d_in[0];
    const int*   ei = (const int*)d_in[1];
    const float* W1 = (const float*)d_in[2];
    const float* b1 = (const float*)d_in[3];
    const float* W2 = (const float*)d_in[4];
    const float* b2 = (const float*)d_in[5];
    float* out = (float*)d_out;
    const int* src = ei;
    const int* dst = ei + N_EDGES;

    char* w = (char*)d_ws;
    __half* hw1h   = (__half*)w;          w += (size_t)N_NODES * HID * 2;   // 12.8 MB
    int*   esrc    = (int*)w;             w += (size_t)N_EDGES * 4;         // 6.4 MB
    unsigned int* rec = (unsigned int*)w; w += (size_t)NB * CAP * 4;        // 9.6 MB
    float* dinv    = (float*)w;           w += (size_t)N_NODES * 4;
    float* hw2s    = (float*)w;           w += (size_t)N_NODES * 2 * 4;
    int*   row_ptr = (int*)w;             w += (size_t)(N_NODES + 1) * 4;
    int*   bcnt    = (int*)w;             w += (size_t)NB * 4;

    hipMemsetAsync(bcnt, 0, NB * sizeof(int), stream);

    k_bin<<<BIN_BLOCKS, 512, 0, stream>>>(src, dst, bcnt, rec);
    k_sort2<<<NB, 512, 0, stream>>>(bcnt, rec, row_ptr, dinv, esrc);
    k_gemm1<<<(N_NODES + 31) / 32, 256, 0, stream>>>(x, W1, dinv, hw1h);
    k_gather1<<<(N_NODES + 15) / 16, 256, 0, stream>>>(row_ptr, esrc, hw1h, dinv, b1, W2, hw2s);
    k_gather2<<<(N_NODES + 63) / 64, 256, 0, stream>>>(row_ptr, esrc, hw2s, dinv, b2, out);
}

// Round 24
// 114.167 us; speedup vs baseline: 1.0631x; 1.0631x over previous
//
#include <hip/hip_runtime.h>
#include <hip/hip_fp16.h>

#define N_NODES 100000
#define N_EDGES 1600000
#define IN_DIM 165
#define HID 64
#define OUT_DIM 2
#define NB ((N_NODES + 127) / 128)               // 782 buckets of 128 nodes
#define CAP 3072                                  // fixed bucket capacity (mean 2048, +22 sigma)
#define EPB 4096                                  // edges per bin block
#define BIN_BLOCKS ((N_EDGES + EPB - 1) / EPB)   // 391
#define KP 64                                     // k-phase (3*64 = 192 >= 165, zero-padded)
#define XST 72                                    // xs row stride in halves (bank-safe)

typedef _Float16 f16x8 __attribute__((ext_vector_type(8)));
typedef float f32x4 __attribute__((ext_vector_type(4)));

// ---- Pass A: bin edges into 782 fixed-capacity bucket regions ----
// Block-local counting sort in LDS, coalesced run write-out.
__global__ __launch_bounds__(512) void k_bin(const int* __restrict__ src,
                                             const int* __restrict__ dst,
                                             int* __restrict__ bcnt,
                                             unsigned int* __restrict__ rec) {
    __shared__ int hist[NB];
    __shared__ int rstart[NB];
    __shared__ int gbase[NB];
    __shared__ int cur[NB];
    __shared__ int tsum[512];
    __shared__ unsigned int lrec[EPB];        // 16 KB
    __shared__ unsigned short lbkt[EPB];      // 8 KB
    const int tid = threadIdx.x;
    for (int b = tid; b < NB; b += 512) { hist[b] = 0; cur[b] = 0; }
    __syncthreads();
    const int e0 = blockIdx.x * EPB;
    const int total = min(EPB, N_EDGES - e0);
    for (int j = tid; j < total; j += 512)
        atomicAdd(&hist[dst[e0 + j] >> 7], 1);
    __syncthreads();
    int own[2];
    int s = 0;
    #pragma unroll
    for (int u = 0; u < 2; ++u) {
        int idx = tid * 2 + u;
        own[u] = s;
        s += (idx < NB) ? hist[idx] : 0;
    }
    tsum[tid] = s;
    __syncthreads();
    for (int off = 1; off < 512; off <<= 1) {
        int t = (tid >= off) ? tsum[tid - off] : 0;
        __syncthreads();
        tsum[tid] += t;
        __syncthreads();
    }
    int prev = (tid > 0) ? tsum[tid - 1] : 0;
    #pragma unroll
    for (int u = 0; u < 2; ++u) {
        int idx = tid * 2 + u;
        if (idx < NB) rstart[idx] = prev + own[u];
    }
    for (int b = tid; b < NB; b += 512)
        if (hist[b] > 0) gbase[b] = atomicAdd(&bcnt[b], hist[b]);
    __syncthreads();
    for (int j = tid; j < total; j += 512) {
        int d = dst[e0 + j], sv = src[e0 + j];
        int b = d >> 7;
        int off = atomicAdd(&cur[b], 1);
        int slot = rstart[b] + off;
        lrec[slot] = (unsigned int)sv | ((unsigned int)(d & 127) << 17);
        lbkt[slot] = (unsigned short)b;
    }
    __syncthreads();
    for (int slot = tid; slot < total; slot += 512) {
        int b = lbkt[slot];
        int pos = gbase[b] + (slot - rstart[b]);
        rec[(size_t)b * CAP + pos] = lrec[slot];
    }
}

// ---- Pass B: per-bucket sort; block computes its own CSR base (no bscan) ----
__global__ __launch_bounds__(512) void k_sort2(const int* __restrict__ bcnt,
                                               const unsigned int* __restrict__ rec,
                                               int* __restrict__ row_ptr,
                                               float* __restrict__ dinv,
                                               int* __restrict__ esrc) {
    __shared__ int hist[128];
    __shared__ int scn[128];
    __shared__ int cur[128];
    __shared__ int tsum[512];
    const int tid = threadIdx.x;
    const int b = blockIdx.x;
    const int n0 = b << 7;
    if (tid < 128) { hist[tid] = 0; cur[tid] = 0; }
    // gb = sum of bcnt[0..b)  (bcnt final at kernel boundary; L2-hot)
    int part = 0;
    for (int j = tid; j < b; j += 512) part += bcnt[j];
    tsum[tid] = part;
    __syncthreads();
    for (int off = 256; off >= 1; off >>= 1) {
        if (tid < off) tsum[tid] += tsum[tid + off];
        __syncthreads();
    }
    const int gb = tsum[0];
    const int cb = bcnt[b];
    const size_t s0 = (size_t)b * CAP;
    // read records ONCE into fixed-index registers + histogram
    unsigned int rv[6];   // 6*512 = 3072 = CAP
    #pragma unroll
    for (int u = 0; u < 6; ++u) {
        int i = tid + (u << 9);
        rv[u] = 0;
        if (i < cb) {
            rv[u] = rec[s0 + i];
            atomicAdd(&hist[rv[u] >> 17], 1);
        }
    }
    __syncthreads();
    int v = (tid < 128) ? hist[tid] : 0;
    if (tid < 128) scn[tid] = v;
    __syncthreads();
    for (int off = 1; off < 128; off <<= 1) {
        int t = (tid >= off && tid < 128) ? scn[tid - off] : 0;
        __syncthreads();
        if (tid < 128) scn[tid] += t;
        __syncthreads();
    }
    if (tid < 128) {
        int n = n0 + tid;
        if (n < N_NODES) {
            row_ptr[n] = gb + scn[tid] - v;            // exclusive base
            dinv[n] = rsqrtf((float)v + 1.0f);
        }
    }
    if (b == NB - 1 && tid == 0) row_ptr[N_NODES] = N_EDGES;
    __syncthreads();
    // place from registers
    #pragma unroll
    for (int u = 0; u < 6; ++u) {
        int i = tid + (u << 9);
        if (i < cb) {
            int ld = (int)(rv[u] >> 17);
            int pos = gb + (scn[ld] - hist[ld]) + atomicAdd(&cur[ld], 1);
            esrc[pos] = (int)(rv[u] & 131071u);
        }
    }
}

// ------- GEMM1 via MFMA: hw1h = fp16((x@W1)*dinv), 32-row tile -------
__global__ __launch_bounds__(256) void k_gemm1(const float* __restrict__ x,
                                               const float* __restrict__ W1,
                                               const float* __restrict__ dinv,
                                               __half* __restrict__ hw1h) {
    __shared__ __align__(16) _Float16 xs[32 * XST];      // 4608 B
    __shared__ __align__(16) _Float16 wsf[8 * 64 * 8];   // 8192 B
    const int tid = threadIdx.x;
    const int lane = tid & 63;
    const int wave = tid >> 6;
    const int lg = lane >> 4;
    const int lm = lane & 15;
    const int mt = wave >> 1;     // M-tile (16 rows)
    const int nh = wave & 1;      // N-half (32 cols)
    const int base = blockIdx.x * 32;
    const int nrows = min(32, N_NODES - base);

    const int srow = tid >> 3;
    const int sseg = (tid & 7) * 8;
    const int src_r = min(srow, nrows - 1);
    const float* xrow = x + (size_t)(base + src_r) * IN_DIM;
    const bool rvalid = (srow < nrows);

    f32x4 acc[2] = {};

    for (int p = 0; p < 3; ++p) {
        const int k0 = p * KP;
        #pragma unroll
        for (int u = 0; u < 8; ++u) {
            int kk = sseg + u;
            int k = k0 + kk;
            float v = xrow[min(k, IN_DIM - 1)];
            xs[srow * XST + kk] = (rvalid && k < IN_DIM) ? (_Float16)v : (_Float16)0.f;
        }
        #pragma unroll
        for (int it = 0; it < 2; ++it) {
            int idx = tid + 256 * it;
            int g = idx >> 6;
            int n = idx & 63;
            f16x8 frag;
            #pragma unroll
            for (int j = 0; j < 8; ++j) {
                int k = k0 + 8 * g + j;
                float v = W1[(size_t)min(k, IN_DIM - 1) * HID + n];
                frag[j] = (k < IN_DIM) ? (_Float16)v : (_Float16)0.f;
            }
            *(f16x8*)&wsf[((g << 6) + n) * 8] = frag;
        }
        __syncthreads();
        #pragma unroll
        for (int s = 0; s < 2; ++s) {
            f16x8 af = *(const f16x8*)&xs[(16 * mt + lm) * XST + 32 * s + 8 * lg];
            #pragma unroll
            for (int nb = 0; nb < 2; ++nb) {
                int nt = 2 * nh + nb;
                f16x8 bf = *(const f16x8*)&wsf[(((s << 2) + lg) * 64 + (nt << 4) + lm) * 8];
                acc[nb] = __builtin_amdgcn_mfma_f32_16x16x32_f16(af, bf, acc[nb], 0, 0, 0);
            }
        }
        __syncthreads();
    }

    #pragma unroll
    for (int r = 0; r < 4; ++r) {
        int grow = base + 16 * mt + 4 * lg + r;
        if (grow < N_NODES) {
            float dv = dinv[grow];
            #pragma unroll
            for (int nb = 0; nb < 2; ++nb) {
                int nt = 2 * nh + nb;
                hw1h[(size_t)grow * HID + (nt << 4) + lm] = __float2half(acc[nb][r] * dv);
            }
        }
    }
}

// ---- layer-1 gather (fp16 rows, 8-deep MLP) + bias/relu + W2 + pre-scale ----
__global__ __launch_bounds__(256) void k_gather1(const int* __restrict__ row_ptr,
                                                 const int* __restrict__ esrc,
                                                 const __half* __restrict__ hw1h,
                                                 const float* __restrict__ dinv,
                                                 const float* __restrict__ b1,
                                                 const float* __restrict__ W2,
                                                 float* __restrict__ hw2s) {
    __shared__ float w2s[HID * OUT_DIM];
    __shared__ float b1s[HID];
    const int tid = threadIdx.x;
    if (tid < HID * OUT_DIM) w2s[tid] = W2[tid];
    if (tid < HID) b1s[tid] = b1[tid];
    __syncthreads();

    const int node = blockIdx.x * 16 + (tid >> 4);
    const int q = tid & 15;
    if (node >= N_NODES) return;
    const int beg = row_ptr[node], end = row_ptr[node + 1];
    float4 acc = {0.f, 0.f, 0.f, 0.f};
    int i = beg;
    for (; i + 7 < end; i += 8) {
        uint2 u[8];
        #pragma unroll
        for (int e = 0; e < 8; ++e) {
            int s = esrc[i + e];
            u[e] = *(const uint2*)&hw1h[(size_t)s * HID + 4 * q];
        }
        #pragma unroll
        for (int e = 0; e < 8; ++e) {
            float2 a0 = __half22float2(*(const __half2*)&u[e].x);
            float2 a1 = __half22float2(*(const __half2*)&u[e].y);
            acc.x += a0.x; acc.y += a0.y; acc.z += a1.x; acc.w += a1.y;
        }
    }
    for (; i + 3 < end; i += 4) {
        uint2 u[4];
        #pragma unroll
        for (int e = 0; e < 4; ++e) {
            int s = esrc[i + e];
            u[e] = *(const uint2*)&hw1h[(size_t)s * HID + 4 * q];
        }
        #pragma unroll
        for (int e = 0; e < 4; ++e) {
            float2 a0 = __half22float2(*(const __half2*)&u[e].x);
            float2 a1 = __half22float2(*(const __half2*)&u[e].y);
            acc.x += a0.x; acc.y += a0.y; acc.z += a1.x; acc.w += a1.y;
        }
    }
    for (; i < end; ++i) {
        int s = esrc[i];
        uint2 u = *(const uint2*)&hw1h[(size_t)s * HID + 4 * q];
        float2 a0 = __half22float2(*(const __half2*)&u.x);
        float2 a1 = __half22float2(*(const __half2*)&u.y);
        acc.x += a0.x; acc.y += a0.y; acc.z += a1.x; acc.w += a1.y;
    }
    const float dv = dinv[node];
    uint2 us = *(const uint2*)&hw1h[(size_t)node * HID + 4 * q];
    float2 h0 = __half22float2(*(const __half2*)&us.x);
    float2 h1 = __half22float2(*(const __half2*)&us.y);
    float h[4];
    h[0] = fmaxf(dv * (acc.x + h0.x) + b1s[4 * q + 0], 0.f);
    h[1] = fmaxf(dv * (acc.y + h0.y) + b1s[4 * q + 1], 0.f);
    h[2] = fmaxf(dv * (acc.z + h1.x) + b1s[4 * q + 2], 0.f);
    h[3] = fmaxf(dv * (acc.w + h1.y) + b1s[4 * q + 3], 0.f);
    float s0 = 0.f, s1 = 0.f;
    #pragma unroll
    for (int k = 0; k < 4; ++k) {
        int j = 4 * q + k;
        s0 += h[k] * w2s[2 * j + 0];
        s1 += h[k] * w2s[2 * j + 1];
    }
    #pragma unroll
    for (int off = 8; off >= 1; off >>= 1) {
        s0 += __shfl_down(s0, off, 16);
        s1 += __shfl_down(s1, off, 16);
    }
    if (q == 0) {
        hw2s[(size_t)node * 2 + 0] = s0 * dv;
        hw2s[(size_t)node * 2 + 1] = s1 * dv;
    }
}

// ---- layer-2 gather (4 lanes/node) + final bias ----
__global__ __launch_bounds__(256) void k_gather2(const int* __restrict__ row_ptr,
                                                 const int* __restrict__ esrc,
                                                 const float* __restrict__ hw2s,
                                                 const float* __restrict__ dinv,
                                                 const float* __restrict__ b2,
                                                 float* __restrict__ out) {
    const int tid = threadIdx.x;
    const int node = blockIdx.x * 64 + (tid >> 2);
    const int e4 = tid & 3;
    if (node >= N_NODES) return;
    const int beg = row_ptr[node], end = row_ptr[node + 1];
    float a0 = 0.f, a1 = 0.f;
    for (int i = beg + e4; i < end; i += 4) {
        int s = esrc[i];
        float2 v = *(const float2*)&hw2s[(size_t)s * 2];
        a0 += v.x;
        a1 += v.y;
    }
    a0 += __shfl_xor(a0, 1, 4); a0 += __shfl_xor(a0, 2, 4);
    a1 += __shfl_xor(a1, 1, 4); a1 += __shfl_xor(a1, 2, 4);
    if (e4 == 0) {
        float dv = dinv[node];
        float2 sv = *(const float2*)&hw2s[(size_t)node * 2];
        out[(size_t)node * 2 + 0] = dv * (a0 + sv.x) + b2[0];
        out[(size_t)node * 2 + 1] = dv * (a1 + sv.y) + b2[1];
    }
}

extern "C" void kernel_launch(void* const* d_in, const int* in_sizes, int n_in,
                              void* d_out, int out_size, void* d_ws, size_t ws_size,
                              hipStream_t stream) {
    const float* x  = (const float*)d_in[0];
    const int*   ei = (const int*)d_in[1];
    const float* W1 = (const float*)d_in[2];
    const float* b1 = (const float*)d_in[3];
    const float* W2 = (const float*)d_in[4];
    const float* b2 = (const float*)d_in[5];
    float* out = (float*)d_out;
    const int* src = ei;
    const int* dst = ei + N_EDGES;

    char* w = (char*)d_ws;
    __half* hw1h   = (__half*)w;          w += (size_t)N_NODES * HID * 2;   // 12.8 MB
    int*   esrc    = (int*)w;             w += (size_t)N_EDGES * 4;         // 6.4 MB
    unsigned int* rec = (unsigned int*)w; w += (size_t)NB * CAP * 4;        // 9.6 MB
    float* dinv    = (float*)w;           w += (size_t)N_NODES * 4;
    float* hw2s    = (float*)w;           w += (size_t)N_NODES * 2 * 4;
    int*   row_ptr = (int*)w;             w += (size_t)(N_NODES + 1) * 4;
    int*   bcnt    = (int*)w;             w += (size_t)NB * 4;

    hipMemsetAsync(bcnt, 0, NB * sizeof(int), stream);

    k_bin<<<BIN_BLOCKS, 512, 0, stream>>>(src, dst, bcnt, rec);
    k_sort2<<<NB, 512, 0, stream>>>(bcnt, rec, row_ptr, dinv, esrc);
    k_gemm1<<<(N_NODES + 31) / 32, 256, 0, stream>>>(x, W1, dinv, hw1h);
    k_gather1<<<(N_NODES + 15) / 16, 256, 0, stream>>>(row_ptr, esrc, hw1h, dinv, b1, W2, hw2s);
    k_gather2<<<(N_NODES + 63) / 64, 256, 0, stream>>>(row_ptr, esrc, hw2s, dinv, b2, out);
}

// Round 25
// 112.629 us; speedup vs baseline: 1.0776x; 1.0137x over previous
//
#include <hip/hip_runtime.h>
#include <hip/hip_fp16.h>

#define N_NODES 100000
#define N_EDGES 1600000
#define IN_DIM 165
#define HID 64
#define OUT_DIM 2
#define NB ((N_NODES + 127) / 128)               // 782 buckets of 128 nodes
#define CAP 3072                                  // fixed bucket capacity (mean 2048, +22 sigma)
#define EPB 6144                                  // edges per bin block (longer runs -> less write-amp)
#define BIN_BLOCKS ((N_EDGES + EPB - 1) / EPB)   // 261
#define KP 64                                     // k-phase (3*64 = 192 >= 165, zero-padded)
#define XST 72                                    // xs row stride in halves (bank-safe)

typedef _Float16 f16x8 __attribute__((ext_vector_type(8)));
typedef float f32x4 __attribute__((ext_vector_type(4)));

// ---- Pass A: bin edges into 782 fixed-capacity bucket regions ----
// Block-local counting sort in LDS, coalesced run write-out.
__global__ __launch_bounds__(512) void k_bin(const int* __restrict__ src,
                                             const int* __restrict__ dst,
                                             int* __restrict__ bcnt,
                                             unsigned int* __restrict__ rec) {
    __shared__ int hist[NB];
    __shared__ int rstart[NB];
    __shared__ int gbase[NB];
    __shared__ int cur[NB];
    __shared__ int tsum[512];
    __shared__ unsigned int lrec[EPB];        // 24 KB
    __shared__ unsigned short lbkt[EPB];      // 12 KB
    const int tid = threadIdx.x;
    for (int b = tid; b < NB; b += 512) { hist[b] = 0; cur[b] = 0; }
    __syncthreads();
    const int e0 = blockIdx.x * EPB;
    const int total = min(EPB, N_EDGES - e0);
    for (int j = tid; j < total; j += 512)
        atomicAdd(&hist[dst[e0 + j] >> 7], 1);
    __syncthreads();
    int own[2];
    int s = 0;
    #pragma unroll
    for (int u = 0; u < 2; ++u) {
        int idx = tid * 2 + u;
        own[u] = s;
        s += (idx < NB) ? hist[idx] : 0;
    }
    tsum[tid] = s;
    __syncthreads();
    for (int off = 1; off < 512; off <<= 1) {
        int t = (tid >= off) ? tsum[tid - off] : 0;
        __syncthreads();
        tsum[tid] += t;
        __syncthreads();
    }
    int prev = (tid > 0) ? tsum[tid - 1] : 0;
    #pragma unroll
    for (int u = 0; u < 2; ++u) {
        int idx = tid * 2 + u;
        if (idx < NB) rstart[idx] = prev + own[u];
    }
    for (int b = tid; b < NB; b += 512)
        if (hist[b] > 0) gbase[b] = atomicAdd(&bcnt[b], hist[b]);
    __syncthreads();
    for (int j = tid; j < total; j += 512) {
        int d = dst[e0 + j], sv = src[e0 + j];
        int b = d >> 7;
        int off = atomicAdd(&cur[b], 1);
        int slot = rstart[b] + off;
        lrec[slot] = (unsigned int)sv | ((unsigned int)(d & 127) << 17);
        lbkt[slot] = (unsigned short)b;
    }
    __syncthreads();
    for (int slot = tid; slot < total; slot += 512) {
        int b = lbkt[slot];
        int pos = gbase[b] + (slot - rstart[b]);
        rec[(size_t)b * CAP + pos] = lrec[slot];
    }
}

// ---- Pass B: per-bucket sort; block computes its own CSR base (no bscan) ----
__global__ __launch_bounds__(512) void k_sort2(const int* __restrict__ bcnt,
                                               const unsigned int* __restrict__ rec,
                                               int* __restrict__ row_ptr,
                                               float* __restrict__ dinv,
                                               int* __restrict__ esrc) {
    __shared__ int hist[128];
    __shared__ int scn[128];
    __shared__ int cur[128];
    __shared__ int tsum[512];
    const int tid = threadIdx.x;
    const int b = blockIdx.x;
    const int n0 = b << 7;
    if (tid < 128) { hist[tid] = 0; cur[tid] = 0; }
    // gb = sum of bcnt[0..b)  (bcnt final at kernel boundary; L2-hot)
    int part = 0;
    for (int j = tid; j < b; j += 512) part += bcnt[j];
    tsum[tid] = part;
    __syncthreads();
    for (int off = 256; off >= 1; off >>= 1) {
        if (tid < off) tsum[tid] += tsum[tid + off];
        __syncthreads();
    }
    const int gb = tsum[0];
    const int cb = bcnt[b];
    const size_t s0 = (size_t)b * CAP;
    // read records ONCE into fixed-index registers + histogram
    unsigned int rv[6];   // 6*512 = 3072 = CAP
    #pragma unroll
    for (int u = 0; u < 6; ++u) {
        int i = tid + (u << 9);
        rv[u] = 0;
        if (i < cb) {
            rv[u] = rec[s0 + i];
            atomicAdd(&hist[rv[u] >> 17], 1);
        }
    }
    __syncthreads();
    int v = (tid < 128) ? hist[tid] : 0;
    if (tid < 128) scn[tid] = v;
    __syncthreads();
    for (int off = 1; off < 128; off <<= 1) {
        int t = (tid >= off && tid < 128) ? scn[tid - off] : 0;
        __syncthreads();
        if (tid < 128) scn[tid] += t;
        __syncthreads();
    }
    if (tid < 128) {
        int n = n0 + tid;
        if (n < N_NODES) {
            row_ptr[n] = gb + scn[tid] - v;            // exclusive base
            dinv[n] = rsqrtf((float)v + 1.0f);
        }
    }
    if (b == NB - 1 && tid == 0) row_ptr[N_NODES] = N_EDGES;
    __syncthreads();
    // place from registers
    #pragma unroll
    for (int u = 0; u < 6; ++u) {
        int i = tid + (u << 9);
        if (i < cb) {
            int ld = (int)(rv[u] >> 17);
            int pos = gb + (scn[ld] - hist[ld]) + atomicAdd(&cur[ld], 1);
            esrc[pos] = (int)(rv[u] & 131071u);
        }
    }
}

// ------- GEMM1 via MFMA: hw1h = fp16((x@W1)*dinv), 32-row tile -------
__global__ __launch_bounds__(256) void k_gemm1(const float* __restrict__ x,
                                               const float* __restrict__ W1,
                                               const float* __restrict__ dinv,
                                               __half* __restrict__ hw1h) {
    __shared__ __align__(16) _Float16 xs[32 * XST];      // 4608 B
    __shared__ __align__(16) _Float16 wsf[8 * 64 * 8];   // 8192 B
    const int tid = threadIdx.x;
    const int lane = tid & 63;
    const int wave = tid >> 6;
    const int lg = lane >> 4;
    const int lm = lane & 15;
    const int mt = wave >> 1;     // M-tile (16 rows)
    const int nh = wave & 1;      // N-half (32 cols)
    const int base = blockIdx.x * 32;
    const int nrows = min(32, N_NODES - base);

    const int srow = tid >> 3;
    const int sseg = (tid & 7) * 8;
    const int src_r = min(srow, nrows - 1);
    const float* xrow = x + (size_t)(base + src_r) * IN_DIM;
    const bool rvalid = (srow < nrows);

    f32x4 acc[2] = {};

    for (int p = 0; p < 3; ++p) {
        const int k0 = p * KP;
        #pragma unroll
        for (int u = 0; u < 8; ++u) {
            int kk = sseg + u;
            int k = k0 + kk;
            float v = xrow[min(k, IN_DIM - 1)];
            xs[srow * XST + kk] = (rvalid && k < IN_DIM) ? (_Float16)v : (_Float16)0.f;
        }
        #pragma unroll
        for (int it = 0; it < 2; ++it) {
            int idx = tid + 256 * it;
            int g = idx >> 6;
            int n = idx & 63;
            f16x8 frag;
            #pragma unroll
            for (int j = 0; j < 8; ++j) {
                int k = k0 + 8 * g + j;
                float v = W1[(size_t)min(k, IN_DIM - 1) * HID + n];
                frag[j] = (k < IN_DIM) ? (_Float16)v : (_Float16)0.f;
            }
            *(f16x8*)&wsf[((g << 6) + n) * 8] = frag;
        }
        __syncthreads();
        #pragma unroll
        for (int s = 0; s < 2; ++s) {
            f16x8 af = *(const f16x8*)&xs[(16 * mt + lm) * XST + 32 * s + 8 * lg];
            #pragma unroll
            for (int nb = 0; nb < 2; ++nb) {
                int nt = 2 * nh + nb;
                f16x8 bf = *(const f16x8*)&wsf[(((s << 2) + lg) * 64 + (nt << 4) + lm) * 8];
                acc[nb] = __builtin_amdgcn_mfma_f32_16x16x32_f16(af, bf, acc[nb], 0, 0, 0);
            }
        }
        __syncthreads();
    }

    #pragma unroll
    for (int r = 0; r < 4; ++r) {
        int grow = base + 16 * mt + 4 * lg + r;
        if (grow < N_NODES) {
            float dv = dinv[grow];
            #pragma unroll
            for (int nb = 0; nb < 2; ++nb) {
                int nt = 2 * nh + nb;
                hw1h[(size_t)grow * HID + (nt << 4) + lm] = __float2half(acc[nb][r] * dv);
            }
        }
    }
}

// ---- layer-1 gather (fp16 rows, 8-deep MLP) + bias/relu + W2 + pre-scale ----
__global__ __launch_bounds__(256) void k_gather1(const int* __restrict__ row_ptr,
                                                 const int* __restrict__ esrc,
                                                 const __half* __restrict__ hw1h,
                                                 const float* __restrict__ dinv,
                                                 const float* __restrict__ b1,
                                                 const float* __restrict__ W2,
                                                 float* __restrict__ hw2s) {
    __shared__ float w2s[HID * OUT_DIM];
    __shared__ float b1s[HID];
    const int tid = threadIdx.x;
    if (tid < HID * OUT_DIM) w2s[tid] = W2[tid];
    if (tid < HID) b1s[tid] = b1[tid];
    __syncthreads();

    const int node = blockIdx.x * 16 + (tid >> 4);
    const int q = tid & 15;
    if (node >= N_NODES) return;
    const int beg = row_ptr[node], end = row_ptr[node + 1];
    float4 acc = {0.f, 0.f, 0.f, 0.f};
    int i = beg;
    for (; i + 7 < end; i += 8) {
        uint2 u[8];
        #pragma unroll
        for (int e = 0; e < 8; ++e) {
            int s = esrc[i + e];
            u[e] = *(const uint2*)&hw1h[(size_t)s * HID + 4 * q];
        }
        #pragma unroll
        for (int e = 0; e < 8; ++e) {
            float2 a0 = __half22float2(*(const __half2*)&u[e].x);
            float2 a1 = __half22float2(*(const __half2*)&u[e].y);
            acc.x += a0.x; acc.y += a0.y; acc.z += a1.x; acc.w += a1.y;
        }
    }
    for (; i + 3 < end; i += 4) {
        uint2 u[4];
        #pragma unroll
        for (int e = 0; e < 4; ++e) {
            int s = esrc[i + e];
            u[e] = *(const uint2*)&hw1h[(size_t)s * HID + 4 * q];
        }
        #pragma unroll
        for (int e = 0; e < 4; ++e) {
            float2 a0 = __half22float2(*(const __half2*)&u[e].x);
            float2 a1 = __half22float2(*(const __half2*)&u[e].y);
            acc.x += a0.x; acc.y += a0.y; acc.z += a1.x; acc.w += a1.y;
        }
    }
    for (; i < end; ++i) {
        int s = esrc[i];
        uint2 u = *(const uint2*)&hw1h[(size_t)s * HID + 4 * q];
        float2 a0 = __half22float2(*(const __half2*)&u.x);
        float2 a1 = __half22float2(*(const __half2*)&u.y);
        acc.x += a0.x; acc.y += a0.y; acc.z += a1.x; acc.w += a1.y;
    }
    const float dv = dinv[node];
    uint2 us = *(const uint2*)&hw1h[(size_t)node * HID + 4 * q];
    float2 h0 = __half22float2(*(const __half2*)&us.x);
    float2 h1 = __half22float2(*(const __half2*)&us.y);
    float h[4];
    h[0] = fmaxf(dv * (acc.x + h0.x) + b1s[4 * q + 0], 0.f);
    h[1] = fmaxf(dv * (acc.y + h0.y) + b1s[4 * q + 1], 0.f);
    h[2] = fmaxf(dv * (acc.z + h1.x) + b1s[4 * q + 2], 0.f);
    h[3] = fmaxf(dv * (acc.w + h1.y) + b1s[4 * q + 3], 0.f);
    float s0 = 0.f, s1 = 0.f;
    #pragma unroll
    for (int k = 0; k < 4; ++k) {
        int j = 4 * q + k;
        s0 += h[k] * w2s[2 * j + 0];
        s1 += h[k] * w2s[2 * j + 1];
    }
    #pragma unroll
    for (int off = 8; off >= 1; off >>= 1) {
        s0 += __shfl_down(s0, off, 16);
        s1 += __shfl_down(s1, off, 16);
    }
    if (q == 0) {
        hw2s[(size_t)node * 2 + 0] = s0 * dv;
        hw2s[(size_t)node * 2 + 1] = s1 * dv;
    }
}

// ---- layer-2 gather (4 lanes/node) + final bias ----
__global__ __launch_bounds__(256) void k_gather2(const int* __restrict__ row_ptr,
                                                 const int* __restrict__ esrc,
                                                 const float* __restrict__ hw2s,
                                                 const float* __restrict__ dinv,
                                                 const float* __restrict__ b2,
                                                 float* __restrict__ out) {
    const int tid = threadIdx.x;
    const int node = blockIdx.x * 64 + (tid >> 2);
    const int e4 = tid & 3;
    if (node >= N_NODES) return;
    const int beg = row_ptr[node], end = row_ptr[node + 1];
    float a0 = 0.f, a1 = 0.f;
    for (int i = beg + e4; i < end; i += 4) {
        int s = esrc[i];
        float2 v = *(const float2*)&hw2s[(size_t)s * 2];
        a0 += v.x;
        a1 += v.y;
    }
    a0 += __shfl_xor(a0, 1, 4); a0 += __shfl_xor(a0, 2, 4);
    a1 += __shfl_xor(a1, 1, 4); a1 += __shfl_xor(a1, 2, 4);
    if (e4 == 0) {
        float dv = dinv[node];
        float2 sv = *(const float2*)&hw2s[(size_t)node * 2];
        out[(size_t)node * 2 + 0] = dv * (a0 + sv.x) + b2[0];
        out[(size_t)node * 2 + 1] = dv * (a1 + sv.y) + b2[1];
    }
}

extern "C" void kernel_launch(void* const* d_in, const int* in_sizes, int n_in,
                              void* d_out, int out_size, void* d_ws, size_t ws_size,
                              hipStream_t stream) {
    const float* x  = (const float*)d_in[0];
    const int*   ei = (const int*)d_in[1];
    const float* W1 = (const float*)d_in[2];
    const float* b1 = (const float*)d_in[3];
    const float* W2 = (const float*)d_in[4];
    const float* b2 = (const float*)d_in[5];
    float* out = (float*)d_out;
    const int* src = ei;
    const int* dst = ei + N_EDGES;

    char* w = (char*)d_ws;
    __half* hw1h   = (__half*)w;          w += (size_t)N_NODES * HID * 2;   // 12.8 MB
    int*   esrc    = (int*)w;             w += (size_t)N_EDGES * 4;         // 6.4 MB
    unsigned int* rec = (unsigned int*)w; w += (size_t)NB * CAP * 4;        // 9.6 MB
    float* dinv    = (float*)w;           w += (size_t)N_NODES * 4;
    float* hw2s    = (float*)w;           w += (size_t)N_NODES * 2 * 4;
    int*   row_ptr = (int*)w;             w += (size_t)(N_NODES + 1) * 4;
    int*   bcnt    = (int*)w;             w += (size_t)NB * 4;

    hipMemsetAsync(bcnt, 0, NB * sizeof(int), stream);

    k_bin<<<BIN_BLOCKS, 512, 0, stream>>>(src, dst, bcnt, rec);
    k_sort2<<<NB, 512, 0, stream>>>(bcnt, rec, row_ptr, dinv, esrc);
    k_gemm1<<<(N_NODES + 31) / 32, 256, 0, stream>>>(x, W1, dinv, hw1h);
    k_gather1<<<(N_NODES + 15) / 16, 256, 0, stream>>>(row_ptr, esrc, hw1h, dinv, b1, W2, hw2s);
    k_gather2<<<(N_NODES + 63) / 64, 256, 0, stream>>>(row_ptr, esrc, hw2s, dinv, b2, out);
}

// Round 26
// 111.264 us; speedup vs baseline: 1.0909x; 1.0123x over previous
//
#include <hip/hip_runtime.h>
#include <hip/hip_fp16.h>

#define N_NODES 100000
#define N_EDGES 1600000
#define IN_DIM 165
#define HID 64
#define OUT_DIM 2
#define NB ((N_NODES + 127) / 128)               // 782 buckets of 128 nodes
#define CAP 3072                                  // fixed bucket capacity (mean 2048, +22 sigma)
#define EPB 8192                                  // edges per bin block (bracket test: runs 10.5 edges)
#define BIN_BLOCKS ((N_EDGES + EPB - 1) / EPB)   // 196
#define KP 64                                     // k-phase (3*64 = 192 >= 165, zero-padded)
#define XST 72                                    // xs row stride in halves (bank-safe)

typedef _Float16 f16x8 __attribute__((ext_vector_type(8)));
typedef float f32x4 __attribute__((ext_vector_type(4)));

// ---- Pass A: bin edges into 782 fixed-capacity bucket regions ----
// Block-local counting sort in LDS, coalesced run write-out.
__global__ __launch_bounds__(512) void k_bin(const int* __restrict__ src,
                                             const int* __restrict__ dst,
                                             int* __restrict__ bcnt,
                                             unsigned int* __restrict__ rec) {
    __shared__ int hist[NB];
    __shared__ int rstart[NB];
    __shared__ int gbase[NB];
    __shared__ int cur[NB];
    __shared__ int tsum[512];
    __shared__ unsigned int lrec[EPB];        // 32 KB
    __shared__ unsigned short lbkt[EPB];      // 16 KB
    const int tid = threadIdx.x;
    for (int b = tid; b < NB; b += 512) { hist[b] = 0; cur[b] = 0; }
    __syncthreads();
    const int e0 = blockIdx.x * EPB;
    const int total = min(EPB, N_EDGES - e0);
    for (int j = tid; j < total; j += 512)
        atomicAdd(&hist[dst[e0 + j] >> 7], 1);
    __syncthreads();
    int own[2];
    int s = 0;
    #pragma unroll
    for (int u = 0; u < 2; ++u) {
        int idx = tid * 2 + u;
        own[u] = s;
        s += (idx < NB) ? hist[idx] : 0;
    }
    tsum[tid] = s;
    __syncthreads();
    for (int off = 1; off < 512; off <<= 1) {
        int t = (tid >= off) ? tsum[tid - off] : 0;
        __syncthreads();
        tsum[tid] += t;
        __syncthreads();
    }
    int prev = (tid > 0) ? tsum[tid - 1] : 0;
    #pragma unroll
    for (int u = 0; u < 2; ++u) {
        int idx = tid * 2 + u;
        if (idx < NB) rstart[idx] = prev + own[u];
    }
    for (int b = tid; b < NB; b += 512)
        if (hist[b] > 0) gbase[b] = atomicAdd(&bcnt[b], hist[b]);
    __syncthreads();
    for (int j = tid; j < total; j += 512) {
        int d = dst[e0 + j], sv = src[e0 + j];
        int b = d >> 7;
        int off = atomicAdd(&cur[b], 1);
        int slot = rstart[b] + off;
        lrec[slot] = (unsigned int)sv | ((unsigned int)(d & 127) << 17);
        lbkt[slot] = (unsigned short)b;
    }
    __syncthreads();
    for (int slot = tid; slot < total; slot += 512) {
        int b = lbkt[slot];
        int pos = gbase[b] + (slot - rstart[b]);
        rec[(size_t)b * CAP + pos] = lrec[slot];
    }
}

// ---- Pass B: per-bucket sort; block computes its own CSR base (no bscan) ----
__global__ __launch_bounds__(512) void k_sort2(const int* __restrict__ bcnt,
                                               const unsigned int* __restrict__ rec,
                                               int* __restrict__ row_ptr,
                                               float* __restrict__ dinv,
                                               int* __restrict__ esrc) {
    __shared__ int hist[128];
    __shared__ int scn[128];
    __shared__ int cur[128];
    __shared__ int tsum[512];
    const int tid = threadIdx.x;
    const int b = blockIdx.x;
    const int n0 = b << 7;
    if (tid < 128) { hist[tid] = 0; cur[tid] = 0; }
    // gb = sum of bcnt[0..b)  (bcnt final at kernel boundary; L2-hot)
    int part = 0;
    for (int j = tid; j < b; j += 512) part += bcnt[j];
    tsum[tid] = part;
    __syncthreads();
    for (int off = 256; off >= 1; off >>= 1) {
        if (tid < off) tsum[tid] += tsum[tid + off];
        __syncthreads();
    }
    const int gb = tsum[0];
    const int cb = bcnt[b];
    const size_t s0 = (size_t)b * CAP;
    // read records ONCE into fixed-index registers + histogram
    unsigned int rv[6];   // 6*512 = 3072 = CAP
    #pragma unroll
    for (int u = 0; u < 6; ++u) {
        int i = tid + (u << 9);
        rv[u] = 0;
        if (i < cb) {
            rv[u] = rec[s0 + i];
            atomicAdd(&hist[rv[u] >> 17], 1);
        }
    }
    __syncthreads();
    int v = (tid < 128) ? hist[tid] : 0;
    if (tid < 128) scn[tid] = v;
    __syncthreads();
    for (int off = 1; off < 128; off <<= 1) {
        int t = (tid >= off && tid < 128) ? scn[tid - off] : 0;
        __syncthreads();
        if (tid < 128) scn[tid] += t;
        __syncthreads();
    }
    if (tid < 128) {
        int n = n0 + tid;
        if (n < N_NODES) {
            row_ptr[n] = gb + scn[tid] - v;            // exclusive base
            dinv[n] = rsqrtf((float)v + 1.0f);
        }
    }
    if (b == NB - 1 && tid == 0) row_ptr[N_NODES] = N_EDGES;
    __syncthreads();
    // place from registers
    #pragma unroll
    for (int u = 0; u < 6; ++u) {
        int i = tid + (u << 9);
        if (i < cb) {
            int ld = (int)(rv[u] >> 17);
            int pos = gb + (scn[ld] - hist[ld]) + atomicAdd(&cur[ld], 1);
            esrc[pos] = (int)(rv[u] & 131071u);
        }
    }
}

// ------- GEMM1 via MFMA: hw1h = fp16((x@W1)*dinv), 32-row tile -------
__global__ __launch_bounds__(256) void k_gemm1(const float* __restrict__ x,
                                               const float* __restrict__ W1,
                                               const float* __restrict__ dinv,
                                               __half* __restrict__ hw1h) {
    __shared__ __align__(16) _Float16 xs[32 * XST];      // 4608 B
    __shared__ __align__(16) _Float16 wsf[8 * 64 * 8];   // 8192 B
    const int tid = threadIdx.x;
    const int lane = tid & 63;
    const int wave = tid >> 6;
    const int lg = lane >> 4;
    const int lm = lane & 15;
    const int mt = wave >> 1;     // M-tile (16 rows)
    const int nh = wave & 1;      // N-half (32 cols)
    const int base = blockIdx.x * 32;
    const int nrows = min(32, N_NODES - base);

    const int srow = tid >> 3;
    const int sseg = (tid & 7) * 8;
    const int src_r = min(srow, nrows - 1);
    const float* xrow = x + (size_t)(base + src_r) * IN_DIM;
    const bool rvalid = (srow < nrows);

    f32x4 acc[2] = {};

    for (int p = 0; p < 3; ++p) {
        const int k0 = p * KP;
        #pragma unroll
        for (int u = 0; u < 8; ++u) {
            int kk = sseg + u;
            int k = k0 + kk;
            float v = xrow[min(k, IN_DIM - 1)];
            xs[srow * XST + kk] = (rvalid && k < IN_DIM) ? (_Float16)v : (_Float16)0.f;
        }
        #pragma unroll
        for (int it = 0; it < 2; ++it) {
            int idx = tid + 256 * it;
            int g = idx >> 6;
            int n = idx & 63;
            f16x8 frag;
            #pragma unroll
            for (int j = 0; j < 8; ++j) {
                int k = k0 + 8 * g + j;
                float v = W1[(size_t)min(k, IN_DIM - 1) * HID + n];
                frag[j] = (k < IN_DIM) ? (_Float16)v : (_Float16)0.f;
            }
            *(f16x8*)&wsf[((g << 6) + n) * 8] = frag;
        }
        __syncthreads();
        #pragma unroll
        for (int s = 0; s < 2; ++s) {
            f16x8 af = *(const f16x8*)&xs[(16 * mt + lm) * XST + 32 * s + 8 * lg];
            #pragma unroll
            for (int nb = 0; nb < 2; ++nb) {
                int nt = 2 * nh + nb;
                f16x8 bf = *(const f16x8*)&wsf[(((s << 2) + lg) * 64 + (nt << 4) + lm) * 8];
                acc[nb] = __builtin_amdgcn_mfma_f32_16x16x32_f16(af, bf, acc[nb], 0, 0, 0);
            }
        }
        __syncthreads();
    }

    #pragma unroll
    for (int r = 0; r < 4; ++r) {
        int grow = base + 16 * mt + 4 * lg + r;
        if (grow < N_NODES) {
            float dv = dinv[grow];
            #pragma unroll
            for (int nb = 0; nb < 2; ++nb) {
                int nt = 2 * nh + nb;
                hw1h[(size_t)grow * HID + (nt << 4) + lm] = __float2half(acc[nb][r] * dv);
            }
        }
    }
}

// ---- layer-1 gather (fp16 rows, 8-deep MLP) + bias/relu + W2 + pre-scale ----
__global__ __launch_bounds__(256) void k_gather1(const int* __restrict__ row_ptr,
                                                 const int* __restrict__ esrc,
                                                 const __half* __restrict__ hw1h,
                                                 const float* __restrict__ dinv,
                                                 const float* __restrict__ b1,
                                                 const float* __restrict__ W2,
                                                 float* __restrict__ hw2s) {
    __shared__ float w2s[HID * OUT_DIM];
    __shared__ float b1s[HID];
    const int tid = threadIdx.x;
    if (tid < HID * OUT_DIM) w2s[tid] = W2[tid];
    if (tid < HID) b1s[tid] = b1[tid];
    __syncthreads();

    const int node = blockIdx.x * 16 + (tid >> 4);
    const int q = tid & 15;
    if (node >= N_NODES) return;
    const int beg = row_ptr[node], end = row_ptr[node + 1];
    float4 acc = {0.f, 0.f, 0.f, 0.f};
    int i = beg;
    for (; i + 7 < end; i += 8) {
        uint2 u[8];
        #pragma unroll
        for (int e = 0; e < 8; ++e) {
            int s = esrc[i + e];
            u[e] = *(const uint2*)&hw1h[(size_t)s * HID + 4 * q];
        }
        #pragma unroll
        for (int e = 0; e < 8; ++e) {
            float2 a0 = __half22float2(*(const __half2*)&u[e].x);
            float2 a1 = __half22float2(*(const __half2*)&u[e].y);
            acc.x += a0.x; acc.y += a0.y; acc.z += a1.x; acc.w += a1.y;
        }
    }
    for (; i + 3 < end; i += 4) {
        uint2 u[4];
        #pragma unroll
        for (int e = 0; e < 4; ++e) {
            int s = esrc[i + e];
            u[e] = *(const uint2*)&hw1h[(size_t)s * HID + 4 * q];
        }
        #pragma unroll
        for (int e = 0; e < 4; ++e) {
            float2 a0 = __half22float2(*(const __half2*)&u[e].x);
            float2 a1 = __half22float2(*(const __half2*)&u[e].y);
            acc.x += a0.x; acc.y += a0.y; acc.z += a1.x; acc.w += a1.y;
        }
    }
    for (; i < end; ++i) {
        int s = esrc[i];
        uint2 u = *(const uint2*)&hw1h[(size_t)s * HID + 4 * q];
        float2 a0 = __half22float2(*(const __half2*)&u.x);
        float2 a1 = __half22float2(*(const __half2*)&u.y);
        acc.x += a0.x; acc.y += a0.y; acc.z += a1.x; acc.w += a1.y;
    }
    const float dv = dinv[node];
    uint2 us = *(const uint2*)&hw1h[(size_t)node * HID + 4 * q];
    float2 h0 = __half22float2(*(const __half2*)&us.x);
    float2 h1 = __half22float2(*(const __half2*)&us.y);
    float h[4];
    h[0] = fmaxf(dv * (acc.x + h0.x) + b1s[4 * q + 0], 0.f);
    h[1] = fmaxf(dv * (acc.y + h0.y) + b1s[4 * q + 1], 0.f);
    h[2] = fmaxf(dv * (acc.z + h1.x) + b1s[4 * q + 2], 0.f);
    h[3] = fmaxf(dv * (acc.w + h1.y) + b1s[4 * q + 3], 0.f);
    float s0 = 0.f, s1 = 0.f;
    #pragma unroll
    for (int k = 0; k < 4; ++k) {
        int j = 4 * q + k;
        s0 += h[k] * w2s[2 * j + 0];
        s1 += h[k] * w2s[2 * j + 1];
    }
    #pragma unroll
    for (int off = 8; off >= 1; off >>= 1) {
        s0 += __shfl_down(s0, off, 16);
        s1 += __shfl_down(s1, off, 16);
    }
    if (q == 0) {
        hw2s[(size_t)node * 2 + 0] = s0 * dv;
        hw2s[(size_t)node * 2 + 1] = s1 * dv;
    }
}

// ---- layer-2 gather (4 lanes/node) + final bias ----
__global__ __launch_bounds__(256) void k_gather2(const int* __restrict__ row_ptr,
                                                 const int* __restrict__ esrc,
                                                 const float* __restrict__ hw2s,
                                                 const float* __restrict__ dinv,
                                                 const float* __restrict__ b2,
                                                 float* __restrict__ out) {
    const int tid = threadIdx.x;
    const int node = blockIdx.x * 64 + (tid >> 2);
    const int e4 = tid & 3;
    if (node >= N_NODES) return;
    const int beg = row_ptr[node], end = row_ptr[node + 1];
    float a0 = 0.f, a1 = 0.f;
    for (int i = beg + e4; i < end; i += 4) {
        int s = esrc[i];
        float2 v = *(const float2*)&hw2s[(size_t)s * 2];
        a0 += v.x;
        a1 += v.y;
    }
    a0 += __shfl_xor(a0, 1, 4); a0 += __shfl_xor(a0, 2, 4);
    a1 += __shfl_xor(a1, 1, 4); a1 += __shfl_xor(a1, 2, 4);
    if (e4 == 0) {
        float dv = dinv[node];
        float2 sv = *(const float2*)&hw2s[(size_t)node * 2];
        out[(size_t)node * 2 + 0] = dv * (a0 + sv.x) + b2[0];
        out[(size_t)node * 2 + 1] = dv * (a1 + sv.y) + b2[1];
    }
}

extern "C" void kernel_launch(void* const* d_in, const int* in_sizes, int n_in,
                              void* d_out, int out_size, void* d_ws, size_t ws_size,
                              hipStream_t stream) {
    const float* x  = (const float*)d_in[0];
    const int*   ei = (const int*)d_in[1];
    const float* W1 = (const float*)d_in[2];
    const float* b1 = (const float*)d_in[3];
    const float* W2 = (const float*)d_in[4];
    const float* b2 = (const float*)d_in[5];
    float* out = (float*)d_out;
    const int* src = ei;
    const int* dst = ei + N_EDGES;

    char* w = (char*)d_ws;
    __half* hw1h   = (__half*)w;          w += (size_t)N_NODES * HID * 2;   // 12.8 MB
    int*   esrc    = (int*)w;             w += (size_t)N_EDGES * 4;         // 6.4 MB
    unsigned int* rec = (unsigned int*)w; w += (size_t)NB * CAP * 4;        // 9.6 MB
    float* dinv    = (float*)w;           w += (size_t)N_NODES * 4;
    float* hw2s    = (float*)w;           w += (size_t)N_NODES * 2 * 4;
    int*   row_ptr = (int*)w;             w += (size_t)(N_NODES + 1) * 4;
    int*   bcnt    = (int*)w;             w += (size_t)NB * 4;

    hipMemsetAsync(bcnt, 0, NB * sizeof(int), stream);

    k_bin<<<BIN_BLOCKS, 512, 0, stream>>>(src, dst, bcnt, rec);
    k_sort2<<<NB, 512, 0, stream>>>(bcnt, rec, row_ptr, dinv, esrc);
    k_gemm1<<<(N_NODES + 31) / 32, 256, 0, stream>>>(x, W1, dinv, hw1h);
    k_gather1<<<(N_NODES + 15) / 16, 256, 0, stream>>>(row_ptr, esrc, hw1h, dinv, b1, W2, hw2s);
    k_gather2<<<(N_NODES + 63) / 64, 256, 0, stream>>>(row_ptr, esrc, hw2s, dinv, b2, out);
}